// Round 8
// baseline (141.159 us; speedup 1.0000x reference)
//
#include <hip/hip_runtime.h>

// APG_Linear: out[b] = ((inp[b] @ U) @ W_b) @ V + bias
//   B=131072, IN=128, OUT=128, RANK=32, all f32. Memory-bound (671 MB, ~102 us floor).
// R7 = R4 (129.9 us) + pair-processing + f16-V:
//   - Two rows per iteration SHARE each u4s ds_read_b128 (U LDS traffic
//     halves: 192 -> 96 cy/row; total LDS ~315 -> ~220 cy/row).
//   - V as packed f16 pairs + v_dot2_f32_f16 in step 3 (-48 VGPR, -46 VALU/row);
//     keeps total VGPR ~115-120 -> natural 4 waves/SIMD. NO forced (256,4) cap
//     (R6's suspected spill mechanism).
//   - Prefetch at loop top (R4 pattern), depth-1 at PAIR granularity.

constexpr int RANK  = 32;
constexpr int BLOCK = 256;            // 4 waves/block
constexpr int WPB   = BLOCK / 64;
constexpr int GRID  = 1024;
constexpr int NWAVES = GRID * WPB;    // 4096 waves; 32 rows/wave = 16 pairs

typedef int    i2_t __attribute__((ext_vector_type(2)));
typedef __fp16 h2_t __attribute__((ext_vector_type(2)));

#define USE_DOT2 (__has_builtin(__builtin_amdgcn_fdot2) && __has_builtin(__builtin_amdgcn_cvt_pkrtz))

// --- VALU-pipe butterfly stages (keep these OFF the LDS pipe) ---
__device__ __forceinline__ float red_xor8(float v) {
#if __has_builtin(__builtin_amdgcn_update_dpp)
    int m = __builtin_amdgcn_update_dpp(0, __float_as_int(v), 0x128, 0xf, 0xf, true);
    return v + __int_as_float(m);
#else
    return v + __shfl_xor(v, 8, 64);
#endif
}
__device__ __forceinline__ float red_xor16(float v) {
#if __has_builtin(__builtin_amdgcn_permlane16_swap)
    i2_t r = __builtin_amdgcn_permlane16_swap(__float_as_int(v), __float_as_int(v),
                                              false, false);
    return __int_as_float(r.x) + __int_as_float(r.y);
#else
    return v + __shfl_xor(v, 16, 64);
#endif
}
__device__ __forceinline__ float red_xor32(float v) {
#if __has_builtin(__builtin_amdgcn_permlane32_swap)
    i2_t r = __builtin_amdgcn_permlane32_swap(__float_as_int(v), __float_as_int(v),
                                              false, false);
    return __int_as_float(r.x) + __int_as_float(r.y);
#else
    return v + __shfl_xor(v, 32, 64);
#endif
}
__device__ __forceinline__ float red_g(float v) {
    return red_xor32(red_xor16(red_xor8(v)));
}

__device__ __forceinline__ h2_t rl_h2(int packed, int srclane) {
    int i = __builtin_amdgcn_readlane(packed, srclane);
    h2_t r; __builtin_memcpy(&r, &i, 4);
    return r;
}
__device__ __forceinline__ int pack_h2(float a, float b) {
#if USE_DOT2
    auto p = __builtin_amdgcn_cvt_pkrtz(a, b);
    int i; __builtin_memcpy(&i, &p, 4);
    return i;
#else
    return 0;
#endif
}

__global__ __launch_bounds__(BLOCK, 2)
void apg_linear_kernel(const float* __restrict__ inp,
                       const float* __restrict__ gw,
                       const float* __restrict__ U,
                       const float* __restrict__ V,
                       const float* __restrict__ bias,
                       float* __restrict__ out,
                       int nrows)
{
    __shared__ float4 u4s[1024];           // U staged: 128x32 f32 = 16 KiB
    __shared__ float  hbuf[WPB][2][RANK];  // per-wave h park, 2 rows (A,B)

    const int tid  = threadIdx.x;
    const int lane = tid & 63;
    const int wid  = tid >> 6;
    const int g    = lane >> 3;         // 0..7

    // ---- stage U into LDS (flat float4 layout: u4s[f] = U[4f..4f+3]) ----
    #pragma unroll
    for (int j = 0; j < 4; ++j)
        u4s[j * BLOCK + tid] = reinterpret_cast<const float4*>(U)[j * BLOCK + tid];
    __syncthreads();

    // ---- V packed as f16 r-pairs: lane owns out cols j0=2*lane, j1=2*lane+1
#if USE_DOT2
    h2_t v2a[16], v2b[16];
    #pragma unroll
    for (int s = 0; s < 16; ++s) {
        const float2 r0 = reinterpret_cast<const float2*>(V + (2*s)     * 128)[lane];
        const float2 r1 = reinterpret_cast<const float2*>(V + (2*s + 1) * 128)[lane];
        v2a[s] = h2_t{(__fp16)r0.x, (__fp16)r1.x};
        v2b[s] = h2_t{(__fp16)r0.y, (__fp16)r1.y};
    }
#else
    float2 v2[RANK];
    #pragma unroll
    for (int r = 0; r < RANK; ++r)
        v2[r] = reinterpret_cast<const float2*>(V + r * 128)[lane];
#endif
    const float2 b2 = reinterpret_cast<const float2*>(bias)[lane];

    float* hwA = hbuf[wid][0];
    float* hwB = hbuf[wid][1];

    const int wave0 = blockIdx.x * WPB + wid;
    const int pairs = (nrows / NWAVES) / 2;       // 16 at B=131072

    // ---- prefetch pair 0 (R4 pattern: fill "n" regs, consume via copy) ----
    int rA = wave0, rB = wave0 + NWAVES;
    float  xA0n = 0.f, xA1n = 0.f, xB0n = 0.f, xB1n = 0.f;
    float4 wAn[4] = {}, wBn[4] = {};
    {
        xA0n = inp[rA * 128 + lane];
        xA1n = inp[rA * 128 + 64 + lane];
        const float4* wpA = reinterpret_cast<const float4*>(gw) + rA * 256;
        #pragma unroll
        for (int t = 0; t < 4; ++t) wAn[t] = wpA[t * 64 + lane];
        xB0n = inp[rB * 128 + lane];
        xB1n = inp[rB * 128 + 64 + lane];
        const float4* wpB = reinterpret_cast<const float4*>(gw) + rB * 256;
        #pragma unroll
        for (int t = 0; t < 4; ++t) wBn[t] = wpB[t * 64 + lane];
    }

    for (int it = 0; it < pairs; ++it) {
        const float xA0 = xA0n, xA1 = xA1n, xB0 = xB0n, xB1 = xB1n;
        float4 wA[4], wB[4];
        #pragma unroll
        for (int t = 0; t < 4; ++t) { wA[t] = wAn[t]; wB[t] = wBn[t]; }
        const int rowA = rA, rowB = rB;

        // ---- prefetch next pair ----
        rA += 2 * NWAVES; rB += 2 * NWAVES;
        if (it + 1 < pairs) {
            xA0n = inp[rA * 128 + lane];
            xA1n = inp[rA * 128 + 64 + lane];
            const float4* wpA = reinterpret_cast<const float4*>(gw) + rA * 256;
            #pragma unroll
            for (int t = 0; t < 4; ++t) wAn[t] = wpA[t * 64 + lane];
            xB0n = inp[rB * 128 + lane];
            xB1n = inp[rB * 128 + 64 + lane];
            const float4* wpB = reinterpret_cast<const float4*>(gw) + rB * 256;
            #pragma unroll
            for (int t = 0; t < 4; ++t) wBn[t] = wpB[t * 64 + lane];
        }

        // ---- step 1 (PAIR-SHARED U reads): h = x @ U for rows A and B ----
        float hA[4] = {0.f, 0.f, 0.f, 0.f};
        float hB[4] = {0.f, 0.f, 0.f, 0.f};
        #pragma unroll
        for (int t = 0; t < 16; ++t) {
            const float4 u  = u4s[t * 64 + lane];          // ONE read, two rows
            const float xsA = (t < 8) ? xA0 : xA1;
            const float xsB = (t < 8) ? xB0 : xB1;
            const int   src = (t & 7) * 8 + g;
            const float xiA = __shfl(xsA, src, 64);
            const float xiB = __shfl(xsB, src, 64);
            hA[0] = fmaf(xiA, u.x, hA[0]);  hB[0] = fmaf(xiB, u.x, hB[0]);
            hA[1] = fmaf(xiA, u.y, hA[1]);  hB[1] = fmaf(xiB, u.y, hB[1]);
            hA[2] = fmaf(xiA, u.z, hA[2]);  hB[2] = fmaf(xiB, u.z, hB[2]);
            hA[3] = fmaf(xiA, u.w, hA[3]);  hB[3] = fmaf(xiB, u.w, hB[3]);
        }
        #pragma unroll
        for (int k = 0; k < 4; ++k) { hA[k] = red_g(hA[k]); hB[k] = red_g(hB[k]); }
        if (lane < 8) {
            reinterpret_cast<float4*>(hwA)[lane] = make_float4(hA[0], hA[1], hA[2], hA[3]);
            reinterpret_cast<float4*>(hwB)[lane] = make_float4(hB[0], hB[1], hB[2], hB[3]);
        }

        // ---- step 2: h2 = h @ W for both rows ----
        float h2A[4] = {0.f, 0.f, 0.f, 0.f};
        float h2B[4] = {0.f, 0.f, 0.f, 0.f};
        #pragma unroll
        for (int t = 0; t < 4; ++t) {
            const float hiA = hwA[t * 8 + g];              // broadcast reads
            const float hiB = hwB[t * 8 + g];
            h2A[0] = fmaf(hiA, wA[t].x, h2A[0]);  h2B[0] = fmaf(hiB, wB[t].x, h2B[0]);
            h2A[1] = fmaf(hiA, wA[t].y, h2A[1]);  h2B[1] = fmaf(hiB, wB[t].y, h2B[1]);
            h2A[2] = fmaf(hiA, wA[t].z, h2A[2]);  h2B[2] = fmaf(hiB, wB[t].z, h2B[2]);
            h2A[3] = fmaf(hiA, wA[t].w, h2A[3]);  h2B[3] = fmaf(hiB, wB[t].w, h2B[3]);
        }
        #pragma unroll
        for (int k = 0; k < 4; ++k) { h2A[k] = red_g(h2A[k]); h2B[k] = red_g(h2B[k]); }

        // ---- step 3: out = h2 @ V + bias (f16 dot2 path) ----
        float oA0 = b2.x, oA1 = b2.y, oB0 = b2.x, oB1 = b2.y;
#if USE_DOT2
        const int pA0 = pack_h2(h2A[0], h2A[1]), pA1 = pack_h2(h2A[2], h2A[3]);
        const int pB0 = pack_h2(h2B[0], h2B[1]), pB1 = pack_h2(h2B[2], h2B[3]);
        #pragma unroll
        for (int c = 0; c < 8; ++c) {
            const h2_t a0 = rl_h2(pA0, c), a1 = rl_h2(pA1, c);
            const h2_t q0 = rl_h2(pB0, c), q1 = rl_h2(pB1, c);
            oA0 = __builtin_amdgcn_fdot2(a0, v2a[2*c],     oA0, false);
            oA1 = __builtin_amdgcn_fdot2(a0, v2b[2*c],     oA1, false);
            oA0 = __builtin_amdgcn_fdot2(a1, v2a[2*c + 1], oA0, false);
            oA1 = __builtin_amdgcn_fdot2(a1, v2b[2*c + 1], oA1, false);
            oB0 = __builtin_amdgcn_fdot2(q0, v2a[2*c],     oB0, false);
            oB1 = __builtin_amdgcn_fdot2(q0, v2b[2*c],     oB1, false);
            oB0 = __builtin_amdgcn_fdot2(q1, v2a[2*c + 1], oB0, false);
            oB1 = __builtin_amdgcn_fdot2(q1, v2b[2*c + 1], oB1, false);
        }
#else
        #pragma unroll
        for (int r = 0; r < RANK; ++r) {
            const float hAr = __uint_as_float(
                __builtin_amdgcn_readlane(__float_as_uint(h2A[r & 3]), r >> 2));
            const float hBr = __uint_as_float(
                __builtin_amdgcn_readlane(__float_as_uint(h2B[r & 3]), r >> 2));
            oA0 = fmaf(hAr, v2[r].x, oA0);  oA1 = fmaf(hAr, v2[r].y, oA1);
            oB0 = fmaf(hBr, v2[r].x, oB0);  oB1 = fmaf(hBr, v2[r].y, oB1);
        }
#endif
        reinterpret_cast<float2*>(out)[rowA * 64 + lane] = make_float2(oA0, oA1);
        reinterpret_cast<float2*>(out)[rowB * 64 + lane] = make_float2(oB0, oB1);
    }
}

extern "C" void kernel_launch(void* const* d_in, const int* in_sizes, int n_in,
                              void* d_out, int out_size, void* d_ws, size_t ws_size,
                              hipStream_t stream)
{
    const float* inp  = (const float*)d_in[0];
    const float* gw   = (const float*)d_in[1];
    const float* U    = (const float*)d_in[2];
    const float* V    = (const float*)d_in[3];
    const float* bias = (const float*)d_in[4];
    float* out = (float*)d_out;
    const int nrows = in_sizes[0] / 128;   // B = 131072 (divisible by 2*NWAVES)

    apg_linear_kernel<<<GRID, BLOCK, 0, stream>>>(inp, gw, U, V, bias, out, nrows);
}

// Round 9
// 137.231 us; speedup vs baseline: 1.0286x; 1.0286x over previous
//
#include <hip/hip_runtime.h>

// APG_Linear: out[b] = ((inp[b] @ U) @ W_b) @ V + bias
//   B=131072, IN=128, OUT=128, RANK=32, all f32. Memory-bound (671 MB, ~107 us floor).
// R8 = R4 (129.9 us) + pair-processing ONLY (f32 everywhere, isolating the
// change R7 bundled with f16-V):
//   - Two rows (A,B) per iteration share each u4s ds_read_b128:
//     LDS/row ~320 -> ~225 cy/CU (U reads 192 -> 96).
//   - Prefetch at pair granularity: x refilled right after step 1 consumes
//     it, wA/wB refilled in place right after each is consumed in step 2
//     (no shadow copies -> W state stays 32 VGPR). 2 rows of compute
//     (~900-1000 cy) now cover the ~900 cy HBM latency (was ~500 cy).
//   - Prefetch rows clamped (branch-free); B=131072 divides 2*NWAVES exactly.
// R6/R7 both landed at 141 with f16-V via two different structures -> f16-V
// path implicated; reverted to f32 V + readlane step 3 (R4's).

constexpr int RANK  = 32;
constexpr int BLOCK = 256;            // 4 waves/block
constexpr int WPB   = BLOCK / 64;
constexpr int GRID  = 1024;
constexpr int NWAVES = GRID * WPB;    // 4096 waves; 32 rows/wave = 16 pairs

typedef int i2_t __attribute__((ext_vector_type(2)));

__device__ __forceinline__ float bcast(float v, int srclane) {
    return __uint_as_float(__builtin_amdgcn_readlane(__float_as_uint(v), srclane));
}

// --- VALU-pipe butterfly stages (keep these OFF the LDS pipe) ---
__device__ __forceinline__ float red_xor8(float v) {
#if __has_builtin(__builtin_amdgcn_update_dpp)
    int m = __builtin_amdgcn_update_dpp(0, __float_as_int(v), 0x128, 0xf, 0xf, true);
    return v + __int_as_float(m);
#else
    return v + __shfl_xor(v, 8, 64);
#endif
}
__device__ __forceinline__ float red_xor16(float v) {
#if __has_builtin(__builtin_amdgcn_permlane16_swap)
    i2_t r = __builtin_amdgcn_permlane16_swap(__float_as_int(v), __float_as_int(v),
                                              false, false);
    return __int_as_float(r.x) + __int_as_float(r.y);
#else
    return v + __shfl_xor(v, 16, 64);
#endif
}
__device__ __forceinline__ float red_xor32(float v) {
#if __has_builtin(__builtin_amdgcn_permlane32_swap)
    i2_t r = __builtin_amdgcn_permlane32_swap(__float_as_int(v), __float_as_int(v),
                                              false, false);
    return __int_as_float(r.x) + __int_as_float(r.y);
#else
    return v + __shfl_xor(v, 32, 64);
#endif
}
__device__ __forceinline__ float red_g(float v) {
    return red_xor32(red_xor16(red_xor8(v)));
}

__global__ __launch_bounds__(BLOCK, 2)
void apg_linear_kernel(const float* __restrict__ inp,
                       const float* __restrict__ gw,
                       const float* __restrict__ U,
                       const float* __restrict__ V,
                       const float* __restrict__ bias,
                       float* __restrict__ out,
                       int nrows)
{
    __shared__ float4 u4s[1024];           // U staged: 128x32 f32 = 16 KiB
    __shared__ float  hbuf[WPB][2][RANK];  // per-wave h park, rows A and B

    const int tid  = threadIdx.x;
    const int lane = tid & 63;
    const int wid  = tid >> 6;
    const int g    = lane >> 3;         // 0..7

    // ---- stage U into LDS (flat float4 layout: u4s[f] = U[4f..4f+3]) ----
    #pragma unroll
    for (int j = 0; j < 4; ++j)
        u4s[j * BLOCK + tid] = reinterpret_cast<const float4*>(U)[j * BLOCK + tid];
    __syncthreads();

    // ---- V and bias in registers: lane owns output cols {2*lane, 2*lane+1} ----
    float2 v2[RANK];
    #pragma unroll
    for (int r = 0; r < RANK; ++r)
        v2[r] = reinterpret_cast<const float2*>(V + r * 128)[lane];
    const float2 b2 = reinterpret_cast<const float2*>(bias)[lane];

    float* hwA = hbuf[wid][0];
    float* hwB = hbuf[wid][1];

    const int wave0 = blockIdx.x * WPB + wid;
    const int pairs = nrows / (2 * NWAVES);   // 16 at B=131072 (exact)

    int rA = wave0, rB = wave0 + NWAVES;

    // ---- prefetch pair 0 ----
    float xA0 = inp[rA * 128 + lane];
    float xA1 = inp[rA * 128 + 64 + lane];
    float xB0 = inp[rB * 128 + lane];
    float xB1 = inp[rB * 128 + 64 + lane];
    float4 wA[4], wB[4];
    {
        const float4* wpA = reinterpret_cast<const float4*>(gw) + rA * 256;
        const float4* wpB = reinterpret_cast<const float4*>(gw) + rB * 256;
        #pragma unroll
        for (int t = 0; t < 4; ++t) { wA[t] = wpA[t * 64 + lane]; wB[t] = wpB[t * 64 + lane]; }
    }

    for (int it = 0; it < pairs; ++it) {
        const int rowA = rA, rowB = rB;
        // clamped next-pair rows (branch-free; last iter redundantly reloads)
        const int nA = (rA + 2 * NWAVES < nrows) ? rA + 2 * NWAVES : rA;
        const int nB = (rB + 2 * NWAVES < nrows) ? rB + 2 * NWAVES : rB;

        // ---- step 1 (PAIR-SHARED U reads): h = x @ U for rows A and B ----
        float hA[4] = {0.f, 0.f, 0.f, 0.f};
        float hB[4] = {0.f, 0.f, 0.f, 0.f};
        #pragma unroll
        for (int t = 0; t < 16; ++t) {
            const float4 u  = u4s[t * 64 + lane];          // ONE read, two rows
            const int   src = (t & 7) * 8 + g;
            const float xiA = __shfl((t < 8) ? xA0 : xA1, src, 64);
            const float xiB = __shfl((t < 8) ? xB0 : xB1, src, 64);
            hA[0] = fmaf(xiA, u.x, hA[0]);  hB[0] = fmaf(xiB, u.x, hB[0]);
            hA[1] = fmaf(xiA, u.y, hA[1]);  hB[1] = fmaf(xiB, u.y, hB[1]);
            hA[2] = fmaf(xiA, u.z, hA[2]);  hB[2] = fmaf(xiB, u.z, hB[2]);
            hA[3] = fmaf(xiA, u.w, hA[3]);  hB[3] = fmaf(xiB, u.w, hB[3]);
        }
        #pragma unroll
        for (int k = 0; k < 4; ++k) { hA[k] = red_g(hA[k]); hB[k] = red_g(hB[k]); }
        if (lane < 8) {
            reinterpret_cast<float4*>(hwA)[lane] = make_float4(hA[0], hA[1], hA[2], hA[3]);
            reinterpret_cast<float4*>(hwB)[lane] = make_float4(hB[0], hB[1], hB[2], hB[3]);
        }

        // ---- x refill for next pair (xA*/xB* dead after step 1) ----
        xA0 = inp[nA * 128 + lane];
        xA1 = inp[nA * 128 + 64 + lane];
        xB0 = inp[nB * 128 + lane];
        xB1 = inp[nB * 128 + 64 + lane];

        // ---- step 2 A: h2A = hA @ W_A, then refill wA in place ----
        float h2A[4] = {0.f, 0.f, 0.f, 0.f};
        #pragma unroll
        for (int t = 0; t < 4; ++t) {
            const float hi = hwA[t * 8 + g];               // broadcast read
            h2A[0] = fmaf(hi, wA[t].x, h2A[0]);
            h2A[1] = fmaf(hi, wA[t].y, h2A[1]);
            h2A[2] = fmaf(hi, wA[t].z, h2A[2]);
            h2A[3] = fmaf(hi, wA[t].w, h2A[3]);
        }
        {
            const float4* wp = reinterpret_cast<const float4*>(gw) + nA * 256;
            #pragma unroll
            for (int t = 0; t < 4; ++t) wA[t] = wp[t * 64 + lane];
        }

        // ---- step 2 B: h2B = hB @ W_B, then refill wB in place ----
        float h2B[4] = {0.f, 0.f, 0.f, 0.f};
        #pragma unroll
        for (int t = 0; t < 4; ++t) {
            const float hi = hwB[t * 8 + g];
            h2B[0] = fmaf(hi, wB[t].x, h2B[0]);
            h2B[1] = fmaf(hi, wB[t].y, h2B[1]);
            h2B[2] = fmaf(hi, wB[t].z, h2B[2]);
            h2B[3] = fmaf(hi, wB[t].w, h2B[3]);
        }
        {
            const float4* wp = reinterpret_cast<const float4*>(gw) + nB * 256;
            #pragma unroll
            for (int t = 0; t < 4; ++t) wB[t] = wp[t * 64 + lane];
        }

        #pragma unroll
        for (int k = 0; k < 4; ++k) { h2A[k] = red_g(h2A[k]); h2B[k] = red_g(h2B[k]); }

        // ---- step 3: out = h2 @ V + bias (readlane broadcasts, f32) ----
        float oA0 = b2.x, oA1 = b2.y, oB0 = b2.x, oB1 = b2.y;
        #pragma unroll
        for (int r = 0; r < RANK; ++r) {
            const float hAr = bcast(h2A[r & 3], r >> 2);
            const float hBr = bcast(h2B[r & 3], r >> 2);
            oA0 = fmaf(hAr, v2[r].x, oA0);  oA1 = fmaf(hAr, v2[r].y, oA1);
            oB0 = fmaf(hBr, v2[r].x, oB0);  oB1 = fmaf(hBr, v2[r].y, oB1);
        }
        reinterpret_cast<float2*>(out)[rowA * 64 + lane] = make_float2(oA0, oA1);
        reinterpret_cast<float2*>(out)[rowB * 64 + lane] = make_float2(oB0, oB1);

        rA = nA; rB = nB;
    }
}

extern "C" void kernel_launch(void* const* d_in, const int* in_sizes, int n_in,
                              void* d_out, int out_size, void* d_ws, size_t ws_size,
                              hipStream_t stream)
{
    const float* inp  = (const float*)d_in[0];
    const float* gw   = (const float*)d_in[1];
    const float* U    = (const float*)d_in[2];
    const float* V    = (const float*)d_in[3];
    const float* bias = (const float*)d_in[4];
    float* out = (float*)d_out;
    const int nrows = in_sizes[0] / 128;   // B = 131072 (divisible by 2*NWAVES)

    apg_linear_kernel<<<GRID, BLOCK, 0, stream>>>(inp, gw, U, V, bias, out, nrows);
}